// Round 23
// baseline (571.021 us; speedup 1.0000x reference)
//
#include <hip/hip_runtime.h>
#include <hip/hip_bf16.h>
#include <stdint.h>

#define CDIV(a, b) (((a) + (b) - 1) / (b))

// Bucketed CSR build: bucket = tgt >> BSH (512 nodes / bucket).
constexpr int BSH = 9;
#define TILE_A 2048

__global__ __launch_bounds__(256) void coarse_hist_k(const int* __restrict__ tgt,
                                                     int* __restrict__ bcnt, int E, int nb) {
    __shared__ int h[512];
    int t = threadIdx.x;
    for (int i = t; i < nb; i += 256) h[i] = 0;
    __syncthreads();
    for (int e = blockIdx.x * 256 + t; e < E; e += gridDim.x * 256)
        atomicAdd(&h[tgt[e] >> BSH], 1);
    __syncthreads();
    for (int i = t; i < nb; i += 256)
        if (h[i]) atomicAdd(&bcnt[i], h[i]);
}

__global__ __launch_bounds__(256) void bucket_scan_k(const int* __restrict__ bcnt,
                                                     int* __restrict__ bbase,
                                                     int* __restrict__ bcur, int nb, int E) {
    __shared__ int sp[256];
    int t = threadIdx.x;
    int c0 = (2 * t < nb) ? bcnt[2 * t] : 0;
    int c1 = (2 * t + 1 < nb) ? bcnt[2 * t + 1] : 0;
    int s2 = c0 + c1;
    sp[t] = s2;
    __syncthreads();
    for (int off = 1; off < 256; off <<= 1) {
        int x = (t >= off) ? sp[t - off] : 0;
        __syncthreads();
        sp[t] += x;
        __syncthreads();
    }
    int excl = sp[t] - s2;
    if (2 * t < nb) { bbase[2 * t] = excl; bcur[2 * t] = excl; }
    if (2 * t + 1 < nb) { bbase[2 * t + 1] = excl + c0; bcur[2 * t + 1] = excl + c0; }
    if (t == 0) bbase[nb] = E;
}

__global__ __launch_bounds__(256) void binA_k(const int* __restrict__ ei,
                                              const int* __restrict__ ea,
                                              int* __restrict__ bcur,
                                              unsigned long long* __restrict__ tmp, int E) {
    __shared__ unsigned long long stage[TILE_A];
    __shared__ int h_cnt[512], h_excl[512], h_cur[512], h_run[512], sp[256];
    int t = threadIdx.x;
    int base = blockIdx.x * TILE_A;
    int nt = min(TILE_A, E - base);
    for (int i = t; i < 512; i += 256) { h_cnt[i] = 0; h_cur[i] = 0; }
    __syncthreads();
    unsigned long long pk[8];
    int bk[8];
#pragma unroll
    for (int k = 0; k < 8; ++k) {
        int e = base + t + k * 256;
        bk[k] = -1;
        if (e < E) {
            int s = ei[e], tg = ei[E + e];
            unsigned a = (unsigned)ea[e];
            pk[k] = ((unsigned long long)(unsigned)tg << 20) |
                    ((unsigned long long)a << 18) | (unsigned long long)(unsigned)s;
            bk[k] = tg >> BSH;
            atomicAdd(&h_cnt[bk[k]], 1);
        }
    }
    __syncthreads();
    int c0 = h_cnt[2 * t], c1 = h_cnt[2 * t + 1];
    int s2 = c0 + c1;
    sp[t] = s2;
    __syncthreads();
    for (int off = 1; off < 256; off <<= 1) {
        int x = (t >= off) ? sp[t - off] : 0;
        __syncthreads();
        sp[t] += x;
        __syncthreads();
    }
    int excl = sp[t] - s2;
    h_excl[2 * t] = excl;
    h_excl[2 * t + 1] = excl + c0;
    __syncthreads();
    for (int i = t; i < 512; i += 256)
        if (h_cnt[i]) h_run[i] = atomicAdd(&bcur[i], h_cnt[i]);
#pragma unroll
    for (int k = 0; k < 8; ++k) {
        if (bk[k] >= 0) {
            int r = atomicAdd(&h_cur[bk[k]], 1);
            stage[h_excl[bk[k]] + r] = pk[k];
        }
    }
    __syncthreads();
    for (int i = t; i < nt; i += 256) {
        unsigned long long v = stage[i];
        int b = (int)(v >> 20) >> BSH;
        tmp[h_run[b] + (i - h_excl[b])] = v;
    }
}

// phase B: per-(node,attr) hist -> rowptr4, attr-sorted adj = (q<<18)|src
__global__ __launch_bounds__(256) void binB_k(const unsigned long long* __restrict__ tmp,
                                              const int* __restrict__ bbase,
                                              unsigned* __restrict__ adj,
                                              int* __restrict__ rowptr4,
                                              float* __restrict__ dinv, int N, int E) {
    __shared__ int ncnt4[2048], nbase4[2048], ncur4[2048], sp[256];
    int t = threadIdx.x, b = blockIdx.x;
    int e0 = bbase[b], e1 = bbase[b + 1];
    int node0 = b << BSH;
    int nn = min(512, N - node0);
    for (int i = t; i < 2048; i += 256) { ncnt4[i] = 0; ncur4[i] = 0; }
    __syncthreads();
    for (int e = e0 + t; e < e1; e += 256) {
        unsigned long long v = tmp[e];
        int li = (int)(v >> 20) - node0;
        int q = (int)(v >> 18) & 3;
        atomicAdd(&ncnt4[li * 4 + q], 1);
    }
    __syncthreads();
    int loc[8];
    int s = 0;
#pragma unroll
    for (int k = 0; k < 8; ++k) { loc[k] = ncnt4[t * 8 + k]; s += loc[k]; }
    sp[t] = s;
    __syncthreads();
    for (int off = 1; off < 256; off <<= 1) {
        int x = (t >= off) ? sp[t - off] : 0;
        __syncthreads();
        sp[t] += x;
        __syncthreads();
    }
    int run = sp[t] - s;
#pragma unroll
    for (int k = 0; k < 8; ++k) { nbase4[t * 8 + k] = run; run += loc[k]; }
    __syncthreads();
    for (int i = t; i < nn; i += 256) {
        int node = node0 + i;
        *(int4*)&rowptr4[node * 4] = make_int4(e0 + nbase4[i * 4], e0 + nbase4[i * 4 + 1],
                                               e0 + nbase4[i * 4 + 2], e0 + nbase4[i * 4 + 3]);
        int c = ncnt4[i * 4] + ncnt4[i * 4 + 1] + ncnt4[i * 4 + 2] + ncnt4[i * 4 + 3];
        dinv[node] = rsqrtf((float)c + 1.0f);
    }
    if (b == 0 && t == 0) rowptr4[N * 4] = E;
    for (int e = e0 + t; e < e1; e += 256) {
        unsigned long long v = tmp[e];
        int li = (int)(v >> 20) - node0;
        int q = (int)(v >> 18) & 3;
        int r = atomicAdd(&ncur4[li * 4 + q], 1);
        adj[e0 + nbase4[li * 4 + q] + r] = (unsigned)(v & 0xFFFFFull);  // (q<<18)|src
    }
}

// ---- degree-descending node permutation (load balance for gather kernels) ----
__global__ __launch_bounds__(256) void dhist_k(const int* __restrict__ rowptr4,
                                               int* __restrict__ dcnt, int N) {
    __shared__ int h[512];
    int t = threadIdx.x;
    for (int i = t; i < 512; i += 256) h[i] = 0;
    __syncthreads();
    for (int node = blockIdx.x * 256 + t; node < N; node += gridDim.x * 256) {
        int deg = min(rowptr4[node * 4 + 4] - rowptr4[node * 4], 511);
        atomicAdd(&h[deg], 1);
    }
    __syncthreads();
    for (int i = t; i < 512; i += 256)
        if (h[i]) atomicAdd(&dcnt[i], h[i]);
}

// dbase[d] = sum_{d' > d} dcnt[d'] (descending-degree order), dcur init
__global__ __launch_bounds__(256) void dscan_k(const int* __restrict__ dcnt,
                                               int* __restrict__ dbase,
                                               int* __restrict__ dcur) {
    __shared__ int sp[256];
    int t = threadIdx.x;
    int c0 = dcnt[511 - 2 * t];
    int c1 = dcnt[511 - (2 * t + 1)];
    int s2 = c0 + c1;
    sp[t] = s2;
    __syncthreads();
    for (int off = 1; off < 256; off <<= 1) {
        int x = (t >= off) ? sp[t - off] : 0;
        __syncthreads();
        sp[t] += x;
        __syncthreads();
    }
    int excl = sp[t] - s2;
    dbase[511 - 2 * t] = excl;       dcur[511 - 2 * t] = excl;
    dbase[511 - 2 * t - 1] = excl + c0; dcur[511 - 2 * t - 1] = excl + c0;
}

__global__ __launch_bounds__(256) void dscatter_k(const int* __restrict__ rowptr4,
                                                  int* __restrict__ dcur,
                                                  int* __restrict__ perm, int N) {
    int node = blockIdx.x * 256 + threadIdx.x;
    if (node < N) {
        int deg = min(rowptr4[node * 4 + 4] - rowptr4[node * 4], 511);
        int pos = atomicAdd(&dcur[deg], 1);
        perm[pos] = node;
    }
}

// batch sorted: gcnt via binary search, no atomics
__device__ __forceinline__ int lb_sorted(const int* __restrict__ b, int n, int g) {
    int lo = 0, hi = n;
    while (lo < hi) {
        int m = (lo + hi) >> 1;
        if (b[m] < g) lo = m + 1; else hi = m;
    }
    return lo;
}

__global__ __launch_bounds__(256) void gbounds_k(const int* __restrict__ batch,
                                                 int* __restrict__ gcnt, int n, int Gn) {
    int g = blockIdx.x * 256 + threadIdx.x;
    if (g < Gn) {
        int a = lb_sorted(batch, n, g);
        int b2 = lb_sorted(batch, n, g + 1);
        gcnt[g] = b2 - a;
    }
}

__device__ __forceinline__ ushort f2bf(float v) {
    __hip_bfloat16 b = __float2bfloat16(v);
    return *reinterpret_cast<ushort*>(&b);
}
__device__ __forceinline__ float bflo(unsigned u) { return __uint_as_float(u << 16); }
__device__ __forceinline__ float bfhi(unsigned u) { return __uint_as_float(u & 0xFFFF0000u); }

// ---------------- GEMM: Y[n,COUT] = (dinv?) * (X[n,K] @ W[K,COUT]) (+bias) ----------------
template <int K, int COUT, int R, typename OutT>
__global__ __launch_bounds__(256) void gemm_rk(const float* __restrict__ X,
                                               const float* __restrict__ W,
                                               const float* __restrict__ bias,
                                               const float* __restrict__ dinv,
                                               OutT* __restrict__ Y, int nrows) {
    constexpr int NCG = COUT / 8;
    constexpr int RG = 256 / NCG;
    constexpr int ROWS = RG * R;
    constexpr int WS = K + 5;
    __shared__ float wt[COUT][WS];
    int t = threadIdx.x;
    for (int i = t; i < K * COUT; i += 256) {
        int k = i / COUT, j = i % COUT;
        wt[j][k] = W[i];
    }
    __syncthreads();
    int cg = t % NCG, g = t / NCG;
    int j0 = cg * 8;
    long rowbase = (long)blockIdx.x * ROWS + (long)g * R;
    float acc[R][8];
#pragma unroll
    for (int r = 0; r < R; ++r)
#pragma unroll
        for (int j = 0; j < 8; ++j) acc[r][j] = 0.0f;

    long rr[R];
#pragma unroll
    for (int r = 0; r < R; ++r) {
        long q = rowbase + r;
        rr[r] = (q < nrows) ? q : (long)(nrows - 1);
    }
    for (int k0 = 0; k0 < K; k0 += 4) {
        float4 xv[R];
#pragma unroll
        for (int r = 0; r < R; ++r) xv[r] = *(const float4*)(X + rr[r] * K + k0);
        float4 wv[8];
#pragma unroll
        for (int j = 0; j < 8; ++j) wv[j] = *(const float4*)&wt[j0 + j][k0];
#pragma unroll
        for (int r = 0; r < R; ++r)
#pragma unroll
            for (int j = 0; j < 8; ++j) {
                acc[r][j] += xv[r].x * wv[j].x;
                acc[r][j] += xv[r].y * wv[j].y;
                acc[r][j] += xv[r].z * wv[j].z;
                acc[r][j] += xv[r].w * wv[j].w;
            }
    }
#pragma unroll
    for (int r = 0; r < R; ++r) {
        long row = rowbase + r;
        if (row < nrows) {
            float dv = dinv ? dinv[row] : 1.0f;
            float o[8];
#pragma unroll
            for (int j = 0; j < 8; ++j) {
                float v = acc[r][j];
                if (bias) v += bias[j0 + j];
                o[j] = v * dv;
            }
            if constexpr (sizeof(OutT) == 4) {
                float4 o0 = make_float4(o[0], o[1], o[2], o[3]);
                float4 o1 = make_float4(o[4], o[5], o[6], o[7]);
                *(float4*)&Y[row * COUT + j0] = o0;
                *(float4*)&Y[row * COUT + j0 + 4] = o1;
            } else {
                uint4 u;
                u.x = (unsigned)f2bf(o[0]) | ((unsigned)f2bf(o[1]) << 16);
                u.y = (unsigned)f2bf(o[2]) | ((unsigned)f2bf(o[3]) << 16);
                u.z = (unsigned)f2bf(o[4]) | ((unsigned)f2bf(o[5]) << 16);
                u.w = (unsigned)f2bf(o[6]) | ((unsigned)f2bf(o[7]) << 16);
                *(uint4*)&Y[row * COUT + j0] = u;
            }
        }
    }
}

// ------- GCN aggregation: 8 lanes/node, ushort4 gathers, perm-balanced -------

template <typename OutT>
__global__ __launch_bounds__(256) void agg_conv_k(const uint2* __restrict__ xwd4,
                                                  const unsigned* __restrict__ adj,
                                                  const int* __restrict__ rowptr4,
                                                  const int* __restrict__ perm,
                                                  const float* __restrict__ dinv,
                                                  const float* __restrict__ bias,
                                                  OutT* __restrict__ out, int n) {
    int t = threadIdx.x;
    int gi = blockIdx.x * 32 + (t >> 3);
    int f4 = t & 7;
    if (gi >= n) return;
    int node = perm[gi];
    int e0 = rowptr4[node * 4];
    int e1 = rowptr4[node * 4 + 4];
    float a0 = 0.f, a1 = 0.f, a2 = 0.f, a3 = 0.f;
    for (int e = e0; e < e1; e += 4) {
        int end1 = e1 - 1;
        int i1 = min(e + 1, end1), i2 = min(e + 2, end1), i3 = min(e + 3, end1);
        unsigned s0 = adj[e] & 0x3FFFF, s1 = adj[i1] & 0x3FFFF;
        unsigned s2 = adj[i2] & 0x3FFFF, s3 = adj[i3] & 0x3FFFF;
        uint2 u0 = xwd4[s0 * 8 + f4];
        uint2 u1 = xwd4[s1 * 8 + f4];
        uint2 u2 = xwd4[s2 * 8 + f4];
        uint2 u3 = xwd4[s3 * 8 + f4];
        bool v1 = e + 1 < e1, v2 = e + 2 < e1, v3 = e + 3 < e1;
        u1.x = v1 ? u1.x : 0u; u1.y = v1 ? u1.y : 0u;
        u2.x = v2 ? u2.x : 0u; u2.y = v2 ? u2.y : 0u;
        u3.x = v3 ? u3.x : 0u; u3.y = v3 ? u3.y : 0u;
        a0 += (bflo(u0.x) + bflo(u1.x)) + (bflo(u2.x) + bflo(u3.x));
        a1 += (bfhi(u0.x) + bfhi(u1.x)) + (bfhi(u2.x) + bfhi(u3.x));
        a2 += (bflo(u0.y) + bflo(u1.y)) + (bflo(u2.y) + bflo(u3.y));
        a3 += (bfhi(u0.y) + bfhi(u1.y)) + (bfhi(u2.y) + bfhi(u3.y));
    }
    float dvn = dinv[node];
    float degv = (float)(e1 - e0) + 1.0f;
    float sself = 1.0f / (dvn * degv);  // xw[node] = xwd[node]/dvn
    uint2 un = xwd4[node * 8 + f4];
    int c0i = 4 * f4;
    float v0 = fmaxf(dvn * a0 + bflo(un.x) * sself + bias[c0i], 0.0f);
    float v1 = fmaxf(dvn * a1 + bfhi(un.x) * sself + bias[c0i + 1], 0.0f);
    float v2 = fmaxf(dvn * a2 + bflo(un.y) * sself + bias[c0i + 2], 0.0f);
    float v3 = fmaxf(dvn * a3 + bfhi(un.y) * sself + bias[c0i + 3], 0.0f);
    if constexpr (sizeof(OutT) == 4) {
        *(float4*)&out[node * 32 + c0i] = make_float4(v0, v1, v2, v3);
    } else {
        uint2 w;
        w.x = (unsigned)f2bf(v0) | ((unsigned)f2bf(v1) << 16);
        w.y = (unsigned)f2bf(v2) | ((unsigned)f2bf(v3) << 16);
        ((uint2*)out)[node * 8 + f4] = w;
    }
}

// ---- fused rs aggregation: per-run 4-windows, ushort4 gathers, perm-balanced,
// accs LDS staging (padded stride, R20-proven) ----
#define RUN_ACC4(START, END, A)                                             \
    for (int e = (START); e < (END); e += 4) {                              \
        int end1 = (END) - 1;                                               \
        int i1 = min(e + 1, end1), i2 = min(e + 2, end1), i3 = min(e + 3, end1); \
        unsigned s0 = adj[e] & 0x3FFFF, s1 = adj[i1] & 0x3FFFF;             \
        unsigned s2 = adj[i2] & 0x3FFFF, s3 = adj[i3] & 0x3FFFF;            \
        uint2 u0 = h2q[s0 * 8 + f4];                                        \
        uint2 u1 = h2q[s1 * 8 + f4];                                        \
        uint2 u2 = h2q[s2 * 8 + f4];                                        \
        uint2 u3 = h2q[s3 * 8 + f4];                                        \
        bool v1 = e + 1 < (END), v2 = e + 2 < (END), v3 = e + 3 < (END);    \
        u1.x = v1 ? u1.x : 0u; u1.y = v1 ? u1.y : 0u;                       \
        u2.x = v2 ? u2.x : 0u; u2.y = v2 ? u2.y : 0u;                       \
        u3.x = v3 ? u3.x : 0u; u3.y = v3 ? u3.y : 0u;                       \
        (A).x += (bflo(u0.x) + bflo(u1.x)) + (bflo(u2.x) + bflo(u3.x));     \
        (A).y += (bfhi(u0.x) + bfhi(u1.x)) + (bfhi(u2.x) + bfhi(u3.x));     \
        (A).z += (bflo(u0.y) + bflo(u1.y)) + (bflo(u2.y) + bflo(u3.y));     \
        (A).w += (bfhi(u0.y) + bfhi(u1.y)) + (bfhi(u2.y) + bfhi(u3.y));     \
    }

__global__ __launch_bounds__(256) void agg_rs_fused_k(const uint2* __restrict__ h2q,
                                                      const unsigned* __restrict__ adj,
                                                      const int* __restrict__ rowptr4,
                                                      const int* __restrict__ perm,
                                                      const float* __restrict__ Wl,
                                                      const float* __restrict__ bl,
                                                      float* __restrict__ out, int n) {
    constexpr int AS = 132;          // accs stride: 132 % 32 = 4 -> no cross-group conflict
    __shared__ float wls[32][128];   // Wl[j][c], 16 KB
    __shared__ float bls[128];
    __shared__ float accs[32][AS];   // per-node A_q staging, 16.9 KB
    int t = threadIdx.x;
    for (int i = t; i < 4096; i += 256) wls[i >> 7][i & 127] = Wl[i];
    if (t < 128) bls[t] = bl[t];
    __syncthreads();

    int nl = t >> 3;
    int f4 = t & 7;
    int c0i = 4 * f4;
    int gi = blockIdx.x * 32 + nl;
    if (gi >= n) return;
    int node = perm[gi];
    int4 rp = *(const int4*)&rowptr4[node * 4];
    int e4 = rowptr4[node * 4 + 4];
    float4 a0 = make_float4(0.f, 0.f, 0.f, 0.f);
    float4 a1 = a0, a2 = a0, a3 = a0;
    RUN_ACC4(rp.x, rp.y, a0)
    RUN_ACC4(rp.y, rp.z, a1)
    RUN_ACC4(rp.z, rp.w, a2)
    RUN_ACC4(rp.w, e4, a3)

    accs[nl][c0i] = a0.x;      accs[nl][c0i + 1] = a0.y;
    accs[nl][c0i + 2] = a0.z;  accs[nl][c0i + 3] = a0.w;
    accs[nl][32 + c0i] = a1.x;     accs[nl][32 + c0i + 1] = a1.y;
    accs[nl][32 + c0i + 2] = a1.z; accs[nl][32 + c0i + 3] = a1.w;
    accs[nl][64 + c0i] = a2.x;     accs[nl][64 + c0i + 1] = a2.y;
    accs[nl][64 + c0i + 2] = a2.z; accs[nl][64 + c0i + 3] = a2.w;
    accs[nl][96 + c0i] = a3.x;     accs[nl][96 + c0i + 1] = a3.y;
    accs[nl][96 + c0i + 2] = a3.z; accs[nl][96 + c0i + 3] = a3.w;
    // wave-local LDS write->read within the 8-lane group (lockstep)
    float m0 = (float)(rp.y - rp.x), m1 = (float)(rp.z - rp.y);
    float m2 = (float)(rp.w - rp.z), m3 = (float)(e4 - rp.w);
    float o0 = m0 * bls[c0i] + m1 * bls[32 + c0i] + m2 * bls[64 + c0i] + m3 * bls[96 + c0i];
    float o1 = m0 * bls[c0i + 1] + m1 * bls[32 + c0i + 1] + m2 * bls[64 + c0i + 1] + m3 * bls[96 + c0i + 1];
    float o2 = m0 * bls[c0i + 2] + m1 * bls[32 + c0i + 2] + m2 * bls[64 + c0i + 2] + m3 * bls[96 + c0i + 2];
    float o3 = m0 * bls[c0i + 3] + m1 * bls[32 + c0i + 3] + m2 * bls[64 + c0i + 3] + m3 * bls[96 + c0i + 3];
#pragma unroll 8
    for (int j = 0; j < 32; ++j) {
        float q0 = accs[nl][j], q1 = accs[nl][32 + j];
        float q2 = accs[nl][64 + j], q3 = accs[nl][96 + j];
        float4 w0 = *(const float4*)&wls[j][c0i];
        float4 w1 = *(const float4*)&wls[j][32 + c0i];
        float4 w2 = *(const float4*)&wls[j][64 + c0i];
        float4 w3 = *(const float4*)&wls[j][96 + c0i];
        o0 += q0 * w0.x + q1 * w1.x + q2 * w2.x + q3 * w3.x;
        o1 += q0 * w0.y + q1 * w1.y + q2 * w2.y + q3 * w3.y;
        o2 += q0 * w0.z + q1 * w1.z + q2 * w2.z + q3 * w3.z;
        o3 += q0 * w0.w + q1 * w1.w + q2 * w2.w + q3 * w3.w;
    }
    float c = fmaxf((float)(e4 - rp.x), 1.0f);
    float ic = 1.0f / c;
    *(float4*)&out[node * 32 + c0i] = make_float4(o0 * ic, o1 * ic, o2 * ic, o3 * ic);
}

// ---------------- graph pooling (batch sorted: boundary-atomic trick) ----------------

__global__ __launch_bounds__(256) void graph_sum_k(const float* __restrict__ agg,
                                                   const int* __restrict__ batch,
                                                   float* __restrict__ gsum, int n) {
    const int CHUNK = 128;
    int t = threadIdx.x;
    int f = t & 31;
    int j = t >> 5;
    long base = (long)blockIdx.x * (8 * CHUNK) + (long)j * CHUNK;
    if (base >= n) return;
    int end = (int)((n - base < CHUNK) ? (n - base) : CHUNK);
    int cur = batch[base];
    float acc = 0.0f;
    for (int i = 0; i < end; ++i) {
        int b = batch[base + i];
        if (b != cur) {
            atomicAdd(&gsum[cur * 32 + f], acc);
            acc = 0.0f;
            cur = b;
        }
        acc += agg[(base + i) * 32 + f];
    }
    atomicAdd(&gsum[cur * 32 + f], acc);
}

// ---------------- final MLP head ----------------

__global__ __launch_bounds__(256) void mlp_k(const float* __restrict__ gsum,
                                             const int* __restrict__ gcnt,
                                             const float* __restrict__ Wm1,
                                             const float* __restrict__ bm1,
                                             const float* __restrict__ Wm2,
                                             const float* __restrict__ bm2,
                                             float* __restrict__ out, int Gn) {
    __shared__ float w1[1024];
    __shared__ float w2[32];
    __shared__ float b1s[32];
    int t = threadIdx.x;
    for (int i = t; i < 1024; i += 256) w1[i] = Wm1[i];
    if (t < 32) {
        w2[t] = Wm2[t];
        b1s[t] = bm1[t];
    }
    __syncthreads();
    if (t < Gn) {
        float inv = 1.0f / fmaxf((float)gcnt[t], 1.0f);
        float gm[32];
#pragma unroll
        for (int k = 0; k < 32; ++k) gm[k] = gsum[t * 32 + k] * inv;
        float o = bm2[0];
        for (int j = 0; j < 32; ++j) {
            float h = b1s[j];
#pragma unroll
            for (int k = 0; k < 32; ++k) h += gm[k] * w1[k * 32 + j];
            o += fmaxf(h, 0.0f) * w2[j];
        }
        out[t] = 1.0f / (1.0f + expf(-o));
    }
}

// ---------------- launch ----------------

extern "C" void kernel_launch(void* const* d_in, const int* in_sizes, int n_in,
                              void* d_out, int out_size, void* d_ws, size_t ws_size,
                              hipStream_t stream) {
    const float* x = (const float*)d_in[0];
    const int* ei = (const int*)d_in[1];
    const int* ea = (const int*)d_in[2];
    const int* batch = (const int*)d_in[3];
    const float* W1 = (const float*)d_in[4];
    const float* b1 = (const float*)d_in[5];
    const float* W2 = (const float*)d_in[6];
    const float* b2 = (const float*)d_in[7];
    const float* Wl = (const float*)d_in[8];
    const float* bl = (const float*)d_in[9];
    const float* Wm1 = (const float*)d_in[10];
    const float* bm1 = (const float*)d_in[11];
    const float* Wm2 = (const float*)d_in[12];
    const float* bm2 = (const float*)d_in[13];

    const int N = in_sizes[3];
    const int E = in_sizes[2];
    const int Gn = out_size;
    const int NBUCKET = CDIV(N, 512);

    char* ws = (char*)d_ws;
    size_t off = 0;
    auto alloc = [&](size_t bytes) -> void* {
        void* p = ws + off;
        off = (off + bytes + 255) & ~(size_t)255;
        return p;
    };
    int* rowptr4 = (int*)alloc((size_t)(4 * N + 4) * 4);
    float* dinv = (float*)alloc((size_t)N * 4);
    int* bcnt = (int*)alloc(512 * 4);
    int* dcnt = (int*)alloc(512 * 4);   // contiguous with bcnt (both 2048B, 256-aligned)
    int* bbase = (int*)alloc(513 * 4);
    int* bcur = (int*)alloc(512 * 4);
    int* dbase = (int*)alloc(512 * 4);
    int* dcur = (int*)alloc(512 * 4);
    int* perm = (int*)alloc((size_t)N * 4);
    unsigned* adj = (unsigned*)alloc((size_t)E * 4);
    float* gsum = (float*)alloc((size_t)Gn * 32 * 4);
    int* gcnt = (int*)alloc((size_t)Gn * 4);
    float* bufA = (float*)alloc((size_t)N * 32 * 4);
    float* bufB = (float*)alloc((size_t)N * 32 * 4);
    ushort* xw_bf = (ushort*)alloc((size_t)N * 32 * 2);
    ushort* h2bf = (ushort*)alloc((size_t)N * 32 * 2);
    unsigned long long* tmp = (unsigned long long*)alloc((size_t)E * 8);

    // Workspace / bucket-capacity guard (output stays zero -> absmax ~0.5 signature).
    if (off > ws_size || NBUCKET > 512) return;

    hipMemsetAsync(bcnt, 0, 1024 * 4, stream);  // covers bcnt + dcnt
    hipMemsetAsync(gsum, 0, (size_t)Gn * 32 * 4, stream);

    coarse_hist_k<<<400, 256, 0, stream>>>(ei + E, bcnt, E, NBUCKET);
    bucket_scan_k<<<1, 256, 0, stream>>>(bcnt, bbase, bcur, NBUCKET, E);
    binA_k<<<CDIV(E, TILE_A), 256, 0, stream>>>(ei, ea, bcur, tmp, E);
    binB_k<<<NBUCKET, 256, 0, stream>>>(tmp, bbase, adj, rowptr4, dinv, N, E);
    // degree-descending permutation for load-balanced gathers
    dhist_k<<<400, 256, 0, stream>>>(rowptr4, dcnt, N);
    dscan_k<<<1, 256, 0, stream>>>(dcnt, dbase, dcur);
    dscatter_k<<<CDIV(N, 256), 256, 0, stream>>>(rowptr4, dcur, perm, N);
    gbounds_k<<<CDIV(Gn, 256), 256, 0, stream>>>(batch, gcnt, N, Gn);

    // conv1: xwd1 = dinv * (x@W1) in bf16; gather (ushort4 lanes); h1 f32
    gemm_rk<128, 32, 1, ushort><<<CDIV(N, 64), 256, 0, stream>>>(x, W1, nullptr, dinv, xw_bf, N);
    agg_conv_k<float><<<CDIV(N, 32), 256, 0, stream>>>((const uint2*)xw_bf, adj, rowptr4,
                                                       perm, dinv, b1, bufB, N);
    // conv2: xwd2 = dinv * (h1@W2) in bf16; gather; h2 bf16
    gemm_rk<32, 32, 1, ushort><<<CDIV(N, 64), 256, 0, stream>>>(bufB, W2, nullptr, dinv, xw_bf, N);
    agg_conv_k<ushort><<<CDIV(N, 32), 256, 0, stream>>>((const uint2*)xw_bf, adj, rowptr4,
                                                        perm, dinv, b2, h2bf, N);
    // fused: agg_rs without materializing hl = h2 @ Wl (ushort4 gathers, accs LDS)
    agg_rs_fused_k<<<CDIV(N, 32), 256, 0, stream>>>((const uint2*)h2bf, adj, rowptr4,
                                                    perm, Wl, bl, bufA, N);
    // graph mean + head
    graph_sum_k<<<CDIV(N, 1024), 256, 0, stream>>>(bufA, batch, gsum, N);
    mlp_k<<<1, 256, 0, stream>>>(gsum, gcnt, Wm1, bm1, Wm2, bm2, (float*)d_out, Gn);
}

// Round 24
// 310.799 us; speedup vs baseline: 1.8373x; 1.8373x over previous
//
#include <hip/hip_runtime.h>
#include <hip/hip_bf16.h>
#include <stdint.h>

#define CDIV(a, b) (((a) + (b) - 1) / (b))

// Bucketed CSR build: bucket = tgt >> BSH (512 nodes / bucket).
constexpr int BSH = 9;
#define TILE_A 2048

__global__ __launch_bounds__(256) void coarse_hist_k(const int* __restrict__ tgt,
                                                     int* __restrict__ bcnt, int E, int nb) {
    __shared__ int h[512];
    int t = threadIdx.x;
    for (int i = t; i < nb; i += 256) h[i] = 0;
    __syncthreads();
    for (int e = blockIdx.x * 256 + t; e < E; e += gridDim.x * 256)
        atomicAdd(&h[tgt[e] >> BSH], 1);
    __syncthreads();
    for (int i = t; i < nb; i += 256)
        if (h[i]) atomicAdd(&bcnt[i], h[i]);
}

__global__ __launch_bounds__(256) void bucket_scan_k(const int* __restrict__ bcnt,
                                                     int* __restrict__ bbase,
                                                     int* __restrict__ bcur, int nb, int E) {
    __shared__ int sp[256];
    int t = threadIdx.x;
    int c0 = (2 * t < nb) ? bcnt[2 * t] : 0;
    int c1 = (2 * t + 1 < nb) ? bcnt[2 * t + 1] : 0;
    int s2 = c0 + c1;
    sp[t] = s2;
    __syncthreads();
    for (int off = 1; off < 256; off <<= 1) {
        int x = (t >= off) ? sp[t - off] : 0;
        __syncthreads();
        sp[t] += x;
        __syncthreads();
    }
    int excl = sp[t] - s2;
    if (2 * t < nb) { bbase[2 * t] = excl; bcur[2 * t] = excl; }
    if (2 * t + 1 < nb) { bbase[2 * t + 1] = excl + c0; bcur[2 * t + 1] = excl + c0; }
    if (t == 0) bbase[nb] = E;
}

__global__ __launch_bounds__(256) void binA_k(const int* __restrict__ ei,
                                              const int* __restrict__ ea,
                                              int* __restrict__ bcur,
                                              unsigned long long* __restrict__ tmp, int E) {
    __shared__ unsigned long long stage[TILE_A];
    __shared__ int h_cnt[512], h_excl[512], h_cur[512], h_run[512], sp[256];
    int t = threadIdx.x;
    int base = blockIdx.x * TILE_A;
    int nt = min(TILE_A, E - base);
    for (int i = t; i < 512; i += 256) { h_cnt[i] = 0; h_cur[i] = 0; }
    __syncthreads();
    unsigned long long pk[8];
    int bk[8];
#pragma unroll
    for (int k = 0; k < 8; ++k) {
        int e = base + t + k * 256;
        bk[k] = -1;
        if (e < E) {
            int s = ei[e], tg = ei[E + e];
            unsigned a = (unsigned)ea[e];
            pk[k] = ((unsigned long long)(unsigned)tg << 20) |
                    ((unsigned long long)a << 18) | (unsigned long long)(unsigned)s;
            bk[k] = tg >> BSH;
            atomicAdd(&h_cnt[bk[k]], 1);
        }
    }
    __syncthreads();
    int c0 = h_cnt[2 * t], c1 = h_cnt[2 * t + 1];
    int s2 = c0 + c1;
    sp[t] = s2;
    __syncthreads();
    for (int off = 1; off < 256; off <<= 1) {
        int x = (t >= off) ? sp[t - off] : 0;
        __syncthreads();
        sp[t] += x;
        __syncthreads();
    }
    int excl = sp[t] - s2;
    h_excl[2 * t] = excl;
    h_excl[2 * t + 1] = excl + c0;
    __syncthreads();
    for (int i = t; i < 512; i += 256)
        if (h_cnt[i]) h_run[i] = atomicAdd(&bcur[i], h_cnt[i]);
#pragma unroll
    for (int k = 0; k < 8; ++k) {
        if (bk[k] >= 0) {
            int r = atomicAdd(&h_cur[bk[k]], 1);
            stage[h_excl[bk[k]] + r] = pk[k];
        }
    }
    __syncthreads();
    for (int i = t; i < nt; i += 256) {
        unsigned long long v = stage[i];
        int b = (int)(v >> 20) >> BSH;
        tmp[h_run[b] + (i - h_excl[b])] = v;
    }
}

// phase B: per-(node,attr) hist -> rowptr4, attr-sorted adj = (q<<18)|src
__global__ __launch_bounds__(256) void binB_k(const unsigned long long* __restrict__ tmp,
                                              const int* __restrict__ bbase,
                                              unsigned* __restrict__ adj,
                                              int* __restrict__ rowptr4,
                                              float* __restrict__ dinv, int N, int E) {
    __shared__ int ncnt4[2048], nbase4[2048], ncur4[2048], sp[256];
    int t = threadIdx.x, b = blockIdx.x;
    int e0 = bbase[b], e1 = bbase[b + 1];
    int node0 = b << BSH;
    int nn = min(512, N - node0);
    for (int i = t; i < 2048; i += 256) { ncnt4[i] = 0; ncur4[i] = 0; }
    __syncthreads();
    for (int e = e0 + t; e < e1; e += 256) {
        unsigned long long v = tmp[e];
        int li = (int)(v >> 20) - node0;
        int q = (int)(v >> 18) & 3;
        atomicAdd(&ncnt4[li * 4 + q], 1);
    }
    __syncthreads();
    int loc[8];
    int s = 0;
#pragma unroll
    for (int k = 0; k < 8; ++k) { loc[k] = ncnt4[t * 8 + k]; s += loc[k]; }
    sp[t] = s;
    __syncthreads();
    for (int off = 1; off < 256; off <<= 1) {
        int x = (t >= off) ? sp[t - off] : 0;
        __syncthreads();
        sp[t] += x;
        __syncthreads();
    }
    int run = sp[t] - s;
#pragma unroll
    for (int k = 0; k < 8; ++k) { nbase4[t * 8 + k] = run; run += loc[k]; }
    __syncthreads();
    for (int i = t; i < nn; i += 256) {
        int node = node0 + i;
        *(int4*)&rowptr4[node * 4] = make_int4(e0 + nbase4[i * 4], e0 + nbase4[i * 4 + 1],
                                               e0 + nbase4[i * 4 + 2], e0 + nbase4[i * 4 + 3]);
        int c = ncnt4[i * 4] + ncnt4[i * 4 + 1] + ncnt4[i * 4 + 2] + ncnt4[i * 4 + 3];
        dinv[node] = rsqrtf((float)c + 1.0f);
    }
    if (b == 0 && t == 0) rowptr4[N * 4] = E;
    for (int e = e0 + t; e < e1; e += 256) {
        unsigned long long v = tmp[e];
        int li = (int)(v >> 20) - node0;
        int q = (int)(v >> 18) & 3;
        int r = atomicAdd(&ncur4[li * 4 + q], 1);
        adj[e0 + nbase4[li * 4 + q] + r] = (unsigned)(v & 0xFFFFFull);  // (q<<18)|src
    }
}

// ---- degree-descending node permutation (load balance for gather kernels) ----
__global__ __launch_bounds__(256) void dhist_k(const int* __restrict__ rowptr4,
                                               int* __restrict__ dcnt, int N) {
    __shared__ int h[512];
    int t = threadIdx.x;
    for (int i = t; i < 512; i += 256) h[i] = 0;
    __syncthreads();
    for (int node = blockIdx.x * 256 + t; node < N; node += gridDim.x * 256) {
        int deg = min(rowptr4[node * 4 + 4] - rowptr4[node * 4], 511);
        atomicAdd(&h[deg], 1);
    }
    __syncthreads();
    for (int i = t; i < 512; i += 256)
        if (h[i]) atomicAdd(&dcnt[i], h[i]);
}

// dbase[d] = sum_{d' > d} dcnt[d'] (descending-degree order), dcur init
__global__ __launch_bounds__(256) void dscan_k(const int* __restrict__ dcnt,
                                               int* __restrict__ dbase,
                                               int* __restrict__ dcur) {
    __shared__ int sp[256];
    int t = threadIdx.x;
    int c0 = dcnt[511 - 2 * t];
    int c1 = dcnt[511 - (2 * t + 1)];
    int s2 = c0 + c1;
    sp[t] = s2;
    __syncthreads();
    for (int off = 1; off < 256; off <<= 1) {
        int x = (t >= off) ? sp[t - off] : 0;
        __syncthreads();
        sp[t] += x;
        __syncthreads();
    }
    int excl = sp[t] - s2;
    dbase[511 - 2 * t] = excl;       dcur[511 - 2 * t] = excl;
    dbase[511 - 2 * t - 1] = excl + c0; dcur[511 - 2 * t - 1] = excl + c0;
}

// two-phase scatter: LDS histogram -> one global atomic per (block,bin) -> LDS cursors
__global__ __launch_bounds__(256) void dscatter_k(const int* __restrict__ rowptr4,
                                                  int* __restrict__ dcur,
                                                  int* __restrict__ perm, int N) {
    __shared__ int h[512], hrun[512], hcur[512];
    int t = threadIdx.x;
    for (int i = t; i < 512; i += 256) { h[i] = 0; hcur[i] = 0; }
    __syncthreads();
    int node = blockIdx.x * 256 + t;
    int deg = -1;
    if (node < N) {
        deg = min(rowptr4[node * 4 + 4] - rowptr4[node * 4], 511);
        atomicAdd(&h[deg], 1);
    }
    __syncthreads();
    for (int i = t; i < 512; i += 256)
        if (h[i]) hrun[i] = atomicAdd(&dcur[i], h[i]);
    __syncthreads();
    if (node < N) {
        int r = atomicAdd(&hcur[deg], 1);
        perm[hrun[deg] + r] = node;
    }
}

// batch sorted: gcnt via binary search, no atomics
__device__ __forceinline__ int lb_sorted(const int* __restrict__ b, int n, int g) {
    int lo = 0, hi = n;
    while (lo < hi) {
        int m = (lo + hi) >> 1;
        if (b[m] < g) lo = m + 1; else hi = m;
    }
    return lo;
}

__global__ __launch_bounds__(256) void gbounds_k(const int* __restrict__ batch,
                                                 int* __restrict__ gcnt, int n, int Gn) {
    int g = blockIdx.x * 256 + threadIdx.x;
    if (g < Gn) {
        int a = lb_sorted(batch, n, g);
        int b2 = lb_sorted(batch, n, g + 1);
        gcnt[g] = b2 - a;
    }
}

__device__ __forceinline__ ushort f2bf(float v) {
    __hip_bfloat16 b = __float2bfloat16(v);
    return *reinterpret_cast<ushort*>(&b);
}
__device__ __forceinline__ float bflo(unsigned u) { return __uint_as_float(u << 16); }
__device__ __forceinline__ float bfhi(unsigned u) { return __uint_as_float(u & 0xFFFF0000u); }

// ---------------- GEMM: Y[n,COUT] = (dinv?) * (X[n,K] @ W[K,COUT]) (+bias) ----------------
template <int K, int COUT, int R, typename OutT>
__global__ __launch_bounds__(256) void gemm_rk(const float* __restrict__ X,
                                               const float* __restrict__ W,
                                               const float* __restrict__ bias,
                                               const float* __restrict__ dinv,
                                               OutT* __restrict__ Y, int nrows) {
    constexpr int NCG = COUT / 8;
    constexpr int RG = 256 / NCG;
    constexpr int ROWS = RG * R;
    constexpr int WS = K + 5;
    __shared__ float wt[COUT][WS];
    int t = threadIdx.x;
    for (int i = t; i < K * COUT; i += 256) {
        int k = i / COUT, j = i % COUT;
        wt[j][k] = W[i];
    }
    __syncthreads();
    int cg = t % NCG, g = t / NCG;
    int j0 = cg * 8;
    long rowbase = (long)blockIdx.x * ROWS + (long)g * R;
    float acc[R][8];
#pragma unroll
    for (int r = 0; r < R; ++r)
#pragma unroll
        for (int j = 0; j < 8; ++j) acc[r][j] = 0.0f;

    long rr[R];
#pragma unroll
    for (int r = 0; r < R; ++r) {
        long q = rowbase + r;
        rr[r] = (q < nrows) ? q : (long)(nrows - 1);
    }
    for (int k0 = 0; k0 < K; k0 += 4) {
        float4 xv[R];
#pragma unroll
        for (int r = 0; r < R; ++r) xv[r] = *(const float4*)(X + rr[r] * K + k0);
        float4 wv[8];
#pragma unroll
        for (int j = 0; j < 8; ++j) wv[j] = *(const float4*)&wt[j0 + j][k0];
#pragma unroll
        for (int r = 0; r < R; ++r)
#pragma unroll
            for (int j = 0; j < 8; ++j) {
                acc[r][j] += xv[r].x * wv[j].x;
                acc[r][j] += xv[r].y * wv[j].y;
                acc[r][j] += xv[r].z * wv[j].z;
                acc[r][j] += xv[r].w * wv[j].w;
            }
    }
#pragma unroll
    for (int r = 0; r < R; ++r) {
        long row = rowbase + r;
        if (row < nrows) {
            float dv = dinv ? dinv[row] : 1.0f;
            float o[8];
#pragma unroll
            for (int j = 0; j < 8; ++j) {
                float v = acc[r][j];
                if (bias) v += bias[j0 + j];
                o[j] = v * dv;
            }
            if constexpr (sizeof(OutT) == 4) {
                float4 o0 = make_float4(o[0], o[1], o[2], o[3]);
                float4 o1 = make_float4(o[4], o[5], o[6], o[7]);
                *(float4*)&Y[row * COUT + j0] = o0;
                *(float4*)&Y[row * COUT + j0 + 4] = o1;
            } else {
                uint4 u;
                u.x = (unsigned)f2bf(o[0]) | ((unsigned)f2bf(o[1]) << 16);
                u.y = (unsigned)f2bf(o[2]) | ((unsigned)f2bf(o[3]) << 16);
                u.z = (unsigned)f2bf(o[4]) | ((unsigned)f2bf(o[5]) << 16);
                u.w = (unsigned)f2bf(o[6]) | ((unsigned)f2bf(o[7]) << 16);
                *(uint4*)&Y[row * COUT + j0] = u;
            }
        }
    }
}

// ------- GCN aggregation: 8 lanes/node, ushort4 gathers, perm-balanced -------

template <typename OutT>
__global__ __launch_bounds__(256) void agg_conv_k(const uint2* __restrict__ xwd4,
                                                  const unsigned* __restrict__ adj,
                                                  const int* __restrict__ rowptr4,
                                                  const int* __restrict__ perm,
                                                  const float* __restrict__ dinv,
                                                  const float* __restrict__ bias,
                                                  OutT* __restrict__ out, int n) {
    int t = threadIdx.x;
    int gi = blockIdx.x * 32 + (t >> 3);
    int f4 = t & 7;
    if (gi >= n) return;
    int node = perm[gi];
    int e0 = rowptr4[node * 4];
    int e1 = rowptr4[node * 4 + 4];
    float a0 = 0.f, a1 = 0.f, a2 = 0.f, a3 = 0.f;
    for (int e = e0; e < e1; e += 4) {
        int end1 = e1 - 1;
        int i1 = min(e + 1, end1), i2 = min(e + 2, end1), i3 = min(e + 3, end1);
        unsigned s0 = adj[e] & 0x3FFFF, s1 = adj[i1] & 0x3FFFF;
        unsigned s2 = adj[i2] & 0x3FFFF, s3 = adj[i3] & 0x3FFFF;
        uint2 u0 = xwd4[s0 * 8 + f4];
        uint2 u1 = xwd4[s1 * 8 + f4];
        uint2 u2 = xwd4[s2 * 8 + f4];
        uint2 u3 = xwd4[s3 * 8 + f4];
        bool v1 = e + 1 < e1, v2 = e + 2 < e1, v3 = e + 3 < e1;
        u1.x = v1 ? u1.x : 0u; u1.y = v1 ? u1.y : 0u;
        u2.x = v2 ? u2.x : 0u; u2.y = v2 ? u2.y : 0u;
        u3.x = v3 ? u3.x : 0u; u3.y = v3 ? u3.y : 0u;
        a0 += (bflo(u0.x) + bflo(u1.x)) + (bflo(u2.x) + bflo(u3.x));
        a1 += (bfhi(u0.x) + bfhi(u1.x)) + (bfhi(u2.x) + bfhi(u3.x));
        a2 += (bflo(u0.y) + bflo(u1.y)) + (bflo(u2.y) + bflo(u3.y));
        a3 += (bfhi(u0.y) + bfhi(u1.y)) + (bfhi(u2.y) + bfhi(u3.y));
    }
    float dvn = dinv[node];
    float degv = (float)(e1 - e0) + 1.0f;
    float sself = 1.0f / (dvn * degv);  // xw[node] = xwd[node]/dvn
    uint2 un = xwd4[node * 8 + f4];
    int c0i = 4 * f4;
    float v0 = fmaxf(dvn * a0 + bflo(un.x) * sself + bias[c0i], 0.0f);
    float v1 = fmaxf(dvn * a1 + bfhi(un.x) * sself + bias[c0i + 1], 0.0f);
    float v2 = fmaxf(dvn * a2 + bflo(un.y) * sself + bias[c0i + 2], 0.0f);
    float v3 = fmaxf(dvn * a3 + bfhi(un.y) * sself + bias[c0i + 3], 0.0f);
    if constexpr (sizeof(OutT) == 4) {
        *(float4*)&out[node * 32 + c0i] = make_float4(v0, v1, v2, v3);
    } else {
        uint2 w;
        w.x = (unsigned)f2bf(v0) | ((unsigned)f2bf(v1) << 16);
        w.y = (unsigned)f2bf(v2) | ((unsigned)f2bf(v3) << 16);
        ((uint2*)out)[node * 8 + f4] = w;
    }
}

// ---- fused rs aggregation: per-run 4-windows, ushort4 gathers, perm-balanced,
// accs LDS staging (padded stride, R20-proven) ----
#define RUN_ACC4(START, END, A)                                             \
    for (int e = (START); e < (END); e += 4) {                              \
        int end1 = (END) - 1;                                               \
        int i1 = min(e + 1, end1), i2 = min(e + 2, end1), i3 = min(e + 3, end1); \
        unsigned s0 = adj[e] & 0x3FFFF, s1 = adj[i1] & 0x3FFFF;             \
        unsigned s2 = adj[i2] & 0x3FFFF, s3 = adj[i3] & 0x3FFFF;            \
        uint2 u0 = h2q[s0 * 8 + f4];                                        \
        uint2 u1 = h2q[s1 * 8 + f4];                                        \
        uint2 u2 = h2q[s2 * 8 + f4];                                        \
        uint2 u3 = h2q[s3 * 8 + f4];                                        \
        bool v1 = e + 1 < (END), v2 = e + 2 < (END), v3 = e + 3 < (END);    \
        u1.x = v1 ? u1.x : 0u; u1.y = v1 ? u1.y : 0u;                       \
        u2.x = v2 ? u2.x : 0u; u2.y = v2 ? u2.y : 0u;                       \
        u3.x = v3 ? u3.x : 0u; u3.y = v3 ? u3.y : 0u;                       \
        (A).x += (bflo(u0.x) + bflo(u1.x)) + (bflo(u2.x) + bflo(u3.x));     \
        (A).y += (bfhi(u0.x) + bfhi(u1.x)) + (bfhi(u2.x) + bfhi(u3.x));     \
        (A).z += (bflo(u0.y) + bflo(u1.y)) + (bflo(u2.y) + bflo(u3.y));     \
        (A).w += (bfhi(u0.y) + bfhi(u1.y)) + (bfhi(u2.y) + bfhi(u3.y));     \
    }

__global__ __launch_bounds__(256) void agg_rs_fused_k(const uint2* __restrict__ h2q,
                                                      const unsigned* __restrict__ adj,
                                                      const int* __restrict__ rowptr4,
                                                      const int* __restrict__ perm,
                                                      const float* __restrict__ Wl,
                                                      const float* __restrict__ bl,
                                                      float* __restrict__ out, int n) {
    constexpr int AS = 132;          // accs stride: 132 % 32 = 4 -> no cross-group conflict
    __shared__ float wls[32][128];   // Wl[j][c], 16 KB
    __shared__ float bls[128];
    __shared__ float accs[32][AS];   // per-node A_q staging, 16.9 KB
    int t = threadIdx.x;
    for (int i = t; i < 4096; i += 256) wls[i >> 7][i & 127] = Wl[i];
    if (t < 128) bls[t] = bl[t];
    __syncthreads();

    int nl = t >> 3;
    int f4 = t & 7;
    int c0i = 4 * f4;
    int gi = blockIdx.x * 32 + nl;
    if (gi >= n) return;
    int node = perm[gi];
    int4 rp = *(const int4*)&rowptr4[node * 4];
    int e4 = rowptr4[node * 4 + 4];
    float4 a0 = make_float4(0.f, 0.f, 0.f, 0.f);
    float4 a1 = a0, a2 = a0, a3 = a0;
    RUN_ACC4(rp.x, rp.y, a0)
    RUN_ACC4(rp.y, rp.z, a1)
    RUN_ACC4(rp.z, rp.w, a2)
    RUN_ACC4(rp.w, e4, a3)

    accs[nl][c0i] = a0.x;      accs[nl][c0i + 1] = a0.y;
    accs[nl][c0i + 2] = a0.z;  accs[nl][c0i + 3] = a0.w;
    accs[nl][32 + c0i] = a1.x;     accs[nl][32 + c0i + 1] = a1.y;
    accs[nl][32 + c0i + 2] = a1.z; accs[nl][32 + c0i + 3] = a1.w;
    accs[nl][64 + c0i] = a2.x;     accs[nl][64 + c0i + 1] = a2.y;
    accs[nl][64 + c0i + 2] = a2.z; accs[nl][64 + c0i + 3] = a2.w;
    accs[nl][96 + c0i] = a3.x;     accs[nl][96 + c0i + 1] = a3.y;
    accs[nl][96 + c0i + 2] = a3.z; accs[nl][96 + c0i + 3] = a3.w;
    // wave-local LDS write->read within the 8-lane group (lockstep)
    float m0 = (float)(rp.y - rp.x), m1 = (float)(rp.z - rp.y);
    float m2 = (float)(rp.w - rp.z), m3 = (float)(e4 - rp.w);
    float o0 = m0 * bls[c0i] + m1 * bls[32 + c0i] + m2 * bls[64 + c0i] + m3 * bls[96 + c0i];
    float o1 = m0 * bls[c0i + 1] + m1 * bls[32 + c0i + 1] + m2 * bls[64 + c0i + 1] + m3 * bls[96 + c0i + 1];
    float o2 = m0 * bls[c0i + 2] + m1 * bls[32 + c0i + 2] + m2 * bls[64 + c0i + 2] + m3 * bls[96 + c0i + 2];
    float o3 = m0 * bls[c0i + 3] + m1 * bls[32 + c0i + 3] + m2 * bls[64 + c0i + 3] + m3 * bls[96 + c0i + 3];
#pragma unroll 8
    for (int j = 0; j < 32; ++j) {
        float q0 = accs[nl][j], q1 = accs[nl][32 + j];
        float q2 = accs[nl][64 + j], q3 = accs[nl][96 + j];
        float4 w0 = *(const float4*)&wls[j][c0i];
        float4 w1 = *(const float4*)&wls[j][32 + c0i];
        float4 w2 = *(const float4*)&wls[j][64 + c0i];
        float4 w3 = *(const float4*)&wls[j][96 + c0i];
        o0 += q0 * w0.x + q1 * w1.x + q2 * w2.x + q3 * w3.x;
        o1 += q0 * w0.y + q1 * w1.y + q2 * w2.y + q3 * w3.y;
        o2 += q0 * w0.z + q1 * w1.z + q2 * w2.z + q3 * w3.z;
        o3 += q0 * w0.w + q1 * w1.w + q2 * w2.w + q3 * w3.w;
    }
    float c = fmaxf((float)(e4 - rp.x), 1.0f);
    float ic = 1.0f / c;
    *(float4*)&out[node * 32 + c0i] = make_float4(o0 * ic, o1 * ic, o2 * ic, o3 * ic);
}

// ---------------- graph pooling (batch sorted: boundary-atomic trick) ----------------

__global__ __launch_bounds__(256) void graph_sum_k(const float* __restrict__ agg,
                                                   const int* __restrict__ batch,
                                                   float* __restrict__ gsum, int n) {
    const int CHUNK = 128;
    int t = threadIdx.x;
    int f = t & 31;
    int j = t >> 5;
    long base = (long)blockIdx.x * (8 * CHUNK) + (long)j * CHUNK;
    if (base >= n) return;
    int end = (int)((n - base < CHUNK) ? (n - base) : CHUNK);
    int cur = batch[base];
    float acc = 0.0f;
    for (int i = 0; i < end; ++i) {
        int b = batch[base + i];
        if (b != cur) {
            atomicAdd(&gsum[cur * 32 + f], acc);
            acc = 0.0f;
            cur = b;
        }
        acc += agg[(base + i) * 32 + f];
    }
    atomicAdd(&gsum[cur * 32 + f], acc);
}

// ---------------- final MLP head ----------------

__global__ __launch_bounds__(256) void mlp_k(const float* __restrict__ gsum,
                                             const int* __restrict__ gcnt,
                                             const float* __restrict__ Wm1,
                                             const float* __restrict__ bm1,
                                             const float* __restrict__ Wm2,
                                             const float* __restrict__ bm2,
                                             float* __restrict__ out, int Gn) {
    __shared__ float w1[1024];
    __shared__ float w2[32];
    __shared__ float b1s[32];
    int t = threadIdx.x;
    for (int i = t; i < 1024; i += 256) w1[i] = Wm1[i];
    if (t < 32) {
        w2[t] = Wm2[t];
        b1s[t] = bm1[t];
    }
    __syncthreads();
    if (t < Gn) {
        float inv = 1.0f / fmaxf((float)gcnt[t], 1.0f);
        float gm[32];
#pragma unroll
        for (int k = 0; k < 32; ++k) gm[k] = gsum[t * 32 + k] * inv;
        float o = bm2[0];
        for (int j = 0; j < 32; ++j) {
            float h = b1s[j];
#pragma unroll
            for (int k = 0; k < 32; ++k) h += gm[k] * w1[k * 32 + j];
            o += fmaxf(h, 0.0f) * w2[j];
        }
        out[t] = 1.0f / (1.0f + expf(-o));
    }
}

// ---------------- launch ----------------

extern "C" void kernel_launch(void* const* d_in, const int* in_sizes, int n_in,
                              void* d_out, int out_size, void* d_ws, size_t ws_size,
                              hipStream_t stream) {
    const float* x = (const float*)d_in[0];
    const int* ei = (const int*)d_in[1];
    const int* ea = (const int*)d_in[2];
    const int* batch = (const int*)d_in[3];
    const float* W1 = (const float*)d_in[4];
    const float* b1 = (const float*)d_in[5];
    const float* W2 = (const float*)d_in[6];
    const float* b2 = (const float*)d_in[7];
    const float* Wl = (const float*)d_in[8];
    const float* bl = (const float*)d_in[9];
    const float* Wm1 = (const float*)d_in[10];
    const float* bm1 = (const float*)d_in[11];
    const float* Wm2 = (const float*)d_in[12];
    const float* bm2 = (const float*)d_in[13];

    const int N = in_sizes[3];
    const int E = in_sizes[2];
    const int Gn = out_size;
    const int NBUCKET = CDIV(N, 512);

    char* ws = (char*)d_ws;
    size_t off = 0;
    auto alloc = [&](size_t bytes) -> void* {
        void* p = ws + off;
        off = (off + bytes + 255) & ~(size_t)255;
        return p;
    };
    int* rowptr4 = (int*)alloc((size_t)(4 * N + 4) * 4);
    float* dinv = (float*)alloc((size_t)N * 4);
    int* bcnt = (int*)alloc(512 * 4);
    int* dcnt = (int*)alloc(512 * 4);   // contiguous with bcnt (both 2048B, 256-aligned)
    int* bbase = (int*)alloc(513 * 4);
    int* bcur = (int*)alloc(512 * 4);
    int* dbase = (int*)alloc(512 * 4);
    int* dcur = (int*)alloc(512 * 4);
    int* perm = (int*)alloc((size_t)N * 4);
    unsigned* adj = (unsigned*)alloc((size_t)E * 4);
    float* gsum = (float*)alloc((size_t)Gn * 32 * 4);
    int* gcnt = (int*)alloc((size_t)Gn * 4);
    float* bufA = (float*)alloc((size_t)N * 32 * 4);
    float* bufB = (float*)alloc((size_t)N * 32 * 4);
    ushort* xw_bf = (ushort*)alloc((size_t)N * 32 * 2);
    ushort* h2bf = (ushort*)alloc((size_t)N * 32 * 2);
    unsigned long long* tmp = (unsigned long long*)alloc((size_t)E * 8);

    // Workspace / bucket-capacity guard (output stays zero -> absmax ~0.5 signature).
    if (off > ws_size || NBUCKET > 512) return;

    hipMemsetAsync(bcnt, 0, 1024 * 4, stream);  // covers bcnt + dcnt
    hipMemsetAsync(gsum, 0, (size_t)Gn * 32 * 4, stream);

    coarse_hist_k<<<400, 256, 0, stream>>>(ei + E, bcnt, E, NBUCKET);
    bucket_scan_k<<<1, 256, 0, stream>>>(bcnt, bbase, bcur, NBUCKET, E);
    binA_k<<<CDIV(E, TILE_A), 256, 0, stream>>>(ei, ea, bcur, tmp, E);
    binB_k<<<NBUCKET, 256, 0, stream>>>(tmp, bbase, adj, rowptr4, dinv, N, E);
    // degree-descending permutation for load-balanced gathers
    dhist_k<<<400, 256, 0, stream>>>(rowptr4, dcnt, N);
    dscan_k<<<1, 256, 0, stream>>>(dcnt, dbase, dcur);
    dscatter_k<<<CDIV(N, 256), 256, 0, stream>>>(rowptr4, dcur, perm, N);
    gbounds_k<<<CDIV(Gn, 256), 256, 0, stream>>>(batch, gcnt, N, Gn);

    // conv1: xwd1 = dinv * (x@W1) in bf16; gather (ushort4 lanes); h1 f32
    gemm_rk<128, 32, 1, ushort><<<CDIV(N, 64), 256, 0, stream>>>(x, W1, nullptr, dinv, xw_bf, N);
    agg_conv_k<float><<<CDIV(N, 32), 256, 0, stream>>>((const uint2*)xw_bf, adj, rowptr4,
                                                       perm, dinv, b1, bufB, N);
    // conv2: xwd2 = dinv * (h1@W2) in bf16; gather; h2 bf16
    gemm_rk<32, 32, 1, ushort><<<CDIV(N, 64), 256, 0, stream>>>(bufB, W2, nullptr, dinv, xw_bf, N);
    agg_conv_k<ushort><<<CDIV(N, 32), 256, 0, stream>>>((const uint2*)xw_bf, adj, rowptr4,
                                                        perm, dinv, b2, h2bf, N);
    // fused: agg_rs without materializing hl = h2 @ Wl (ushort4 gathers, accs LDS)
    agg_rs_fused_k<<<CDIV(N, 32), 256, 0, stream>>>((const uint2*)h2bf, adj, rowptr4,
                                                    perm, Wl, bl, bufA, N);
    // graph mean + head
    graph_sum_k<<<CDIV(N, 1024), 256, 0, stream>>>(bufA, batch, gsum, N);
    mlp_k<<<1, 256, 0, stream>>>(gsum, gcnt, Wm1, bm1, Wm2, bm2, (float*)d_out, Gn);
}

// Round 25
// 288.378 us; speedup vs baseline: 1.9801x; 1.0777x over previous
//
#include <hip/hip_runtime.h>
#include <hip/hip_bf16.h>
#include <stdint.h>

#define CDIV(a, b) (((a) + (b) - 1) / (b))

// Bucketed CSR build: bucket = tgt >> BSH (512 nodes / bucket).
constexpr int BSH = 9;
#define TILE_A 2048

__global__ __launch_bounds__(256) void coarse_hist_k(const int* __restrict__ tgt,
                                                     int* __restrict__ bcnt, int E, int nb) {
    __shared__ int h[512];
    int t = threadIdx.x;
    for (int i = t; i < nb; i += 256) h[i] = 0;
    __syncthreads();
    for (int e = blockIdx.x * 256 + t; e < E; e += gridDim.x * 256)
        atomicAdd(&h[tgt[e] >> BSH], 1);
    __syncthreads();
    for (int i = t; i < nb; i += 256)
        if (h[i]) atomicAdd(&bcnt[i], h[i]);
}

__global__ __launch_bounds__(256) void bucket_scan_k(const int* __restrict__ bcnt,
                                                     int* __restrict__ bbase,
                                                     int* __restrict__ bcur, int nb, int E) {
    __shared__ int sp[256];
    int t = threadIdx.x;
    int c0 = (2 * t < nb) ? bcnt[2 * t] : 0;
    int c1 = (2 * t + 1 < nb) ? bcnt[2 * t + 1] : 0;
    int s2 = c0 + c1;
    sp[t] = s2;
    __syncthreads();
    for (int off = 1; off < 256; off <<= 1) {
        int x = (t >= off) ? sp[t - off] : 0;
        __syncthreads();
        sp[t] += x;
        __syncthreads();
    }
    int excl = sp[t] - s2;
    if (2 * t < nb) { bbase[2 * t] = excl; bcur[2 * t] = excl; }
    if (2 * t + 1 < nb) { bbase[2 * t + 1] = excl + c0; bcur[2 * t + 1] = excl + c0; }
    if (t == 0) bbase[nb] = E;
}

__global__ __launch_bounds__(256) void binA_k(const int* __restrict__ ei,
                                              const int* __restrict__ ea,
                                              int* __restrict__ bcur,
                                              unsigned long long* __restrict__ tmp, int E) {
    __shared__ unsigned long long stage[TILE_A];
    __shared__ int h_cnt[512], h_excl[512], h_cur[512], h_run[512], sp[256];
    int t = threadIdx.x;
    int base = blockIdx.x * TILE_A;
    int nt = min(TILE_A, E - base);
    for (int i = t; i < 512; i += 256) { h_cnt[i] = 0; h_cur[i] = 0; }
    __syncthreads();
    unsigned long long pk[8];
    int bk[8];
#pragma unroll
    for (int k = 0; k < 8; ++k) {
        int e = base + t + k * 256;
        bk[k] = -1;
        if (e < E) {
            int s = ei[e], tg = ei[E + e];
            unsigned a = (unsigned)ea[e];
            pk[k] = ((unsigned long long)(unsigned)tg << 20) |
                    ((unsigned long long)a << 18) | (unsigned long long)(unsigned)s;
            bk[k] = tg >> BSH;
            atomicAdd(&h_cnt[bk[k]], 1);
        }
    }
    __syncthreads();
    int c0 = h_cnt[2 * t], c1 = h_cnt[2 * t + 1];
    int s2 = c0 + c1;
    sp[t] = s2;
    __syncthreads();
    for (int off = 1; off < 256; off <<= 1) {
        int x = (t >= off) ? sp[t - off] : 0;
        __syncthreads();
        sp[t] += x;
        __syncthreads();
    }
    int excl = sp[t] - s2;
    h_excl[2 * t] = excl;
    h_excl[2 * t + 1] = excl + c0;
    __syncthreads();
    for (int i = t; i < 512; i += 256)
        if (h_cnt[i]) h_run[i] = atomicAdd(&bcur[i], h_cnt[i]);
#pragma unroll
    for (int k = 0; k < 8; ++k) {
        if (bk[k] >= 0) {
            int r = atomicAdd(&h_cur[bk[k]], 1);
            stage[h_excl[bk[k]] + r] = pk[k];
        }
    }
    __syncthreads();
    for (int i = t; i < nt; i += 256) {
        unsigned long long v = stage[i];
        int b = (int)(v >> 20) >> BSH;
        tmp[h_run[b] + (i - h_excl[b])] = v;
    }
}

// phase B: per-(node,attr) hist -> rowptr4, attr-sorted adj = (q<<18)|src
__global__ __launch_bounds__(256) void binB_k(const unsigned long long* __restrict__ tmp,
                                              const int* __restrict__ bbase,
                                              unsigned* __restrict__ adj,
                                              int* __restrict__ rowptr4,
                                              float* __restrict__ dinv, int N, int E) {
    __shared__ int ncnt4[2048], nbase4[2048], ncur4[2048], sp[256];
    int t = threadIdx.x, b = blockIdx.x;
    int e0 = bbase[b], e1 = bbase[b + 1];
    int node0 = b << BSH;
    int nn = min(512, N - node0);
    for (int i = t; i < 2048; i += 256) { ncnt4[i] = 0; ncur4[i] = 0; }
    __syncthreads();
    for (int e = e0 + t; e < e1; e += 256) {
        unsigned long long v = tmp[e];
        int li = (int)(v >> 20) - node0;
        int q = (int)(v >> 18) & 3;
        atomicAdd(&ncnt4[li * 4 + q], 1);
    }
    __syncthreads();
    int loc[8];
    int s = 0;
#pragma unroll
    for (int k = 0; k < 8; ++k) { loc[k] = ncnt4[t * 8 + k]; s += loc[k]; }
    sp[t] = s;
    __syncthreads();
    for (int off = 1; off < 256; off <<= 1) {
        int x = (t >= off) ? sp[t - off] : 0;
        __syncthreads();
        sp[t] += x;
        __syncthreads();
    }
    int run = sp[t] - s;
#pragma unroll
    for (int k = 0; k < 8; ++k) { nbase4[t * 8 + k] = run; run += loc[k]; }
    __syncthreads();
    for (int i = t; i < nn; i += 256) {
        int node = node0 + i;
        *(int4*)&rowptr4[node * 4] = make_int4(e0 + nbase4[i * 4], e0 + nbase4[i * 4 + 1],
                                               e0 + nbase4[i * 4 + 2], e0 + nbase4[i * 4 + 3]);
        int c = ncnt4[i * 4] + ncnt4[i * 4 + 1] + ncnt4[i * 4 + 2] + ncnt4[i * 4 + 3];
        dinv[node] = rsqrtf((float)c + 1.0f);
    }
    if (b == 0 && t == 0) rowptr4[N * 4] = E;
    for (int e = e0 + t; e < e1; e += 256) {
        unsigned long long v = tmp[e];
        int li = (int)(v >> 20) - node0;
        int q = (int)(v >> 18) & 3;
        int r = atomicAdd(&ncur4[li * 4 + q], 1);
        adj[e0 + nbase4[li * 4 + q] + r] = (unsigned)(v & 0xFFFFFull);  // (q<<18)|src
    }
}

// batch sorted: gcnt via binary search, no atomics
__device__ __forceinline__ int lb_sorted(const int* __restrict__ b, int n, int g) {
    int lo = 0, hi = n;
    while (lo < hi) {
        int m = (lo + hi) >> 1;
        if (b[m] < g) lo = m + 1; else hi = m;
    }
    return lo;
}

__global__ __launch_bounds__(256) void gbounds_k(const int* __restrict__ batch,
                                                 int* __restrict__ gcnt, int n, int Gn) {
    int g = blockIdx.x * 256 + threadIdx.x;
    if (g < Gn) {
        int a = lb_sorted(batch, n, g);
        int b2 = lb_sorted(batch, n, g + 1);
        gcnt[g] = b2 - a;
    }
}

__device__ __forceinline__ ushort f2bf(float v) {
    __hip_bfloat16 b = __float2bfloat16(v);
    return *reinterpret_cast<ushort*>(&b);
}
__device__ __forceinline__ float bflo(unsigned u) { return __uint_as_float(u << 16); }
__device__ __forceinline__ float bfhi(unsigned u) { return __uint_as_float(u & 0xFFFF0000u); }

// ---------------- GEMM: Y[n,COUT] = (dinv?) * (X[n,K] @ W[K,COUT]) (+bias) ----------------
template <int K, int COUT, int R, typename OutT>
__global__ __launch_bounds__(256) void gemm_rk(const float* __restrict__ X,
                                               const float* __restrict__ W,
                                               const float* __restrict__ bias,
                                               const float* __restrict__ dinv,
                                               OutT* __restrict__ Y, int nrows) {
    constexpr int NCG = COUT / 8;
    constexpr int RG = 256 / NCG;
    constexpr int ROWS = RG * R;
    constexpr int WS = K + 5;
    __shared__ float wt[COUT][WS];
    int t = threadIdx.x;
    for (int i = t; i < K * COUT; i += 256) {
        int k = i / COUT, j = i % COUT;
        wt[j][k] = W[i];
    }
    __syncthreads();
    int cg = t % NCG, g = t / NCG;
    int j0 = cg * 8;
    long rowbase = (long)blockIdx.x * ROWS + (long)g * R;
    float acc[R][8];
#pragma unroll
    for (int r = 0; r < R; ++r)
#pragma unroll
        for (int j = 0; j < 8; ++j) acc[r][j] = 0.0f;

    long rr[R];
#pragma unroll
    for (int r = 0; r < R; ++r) {
        long q = rowbase + r;
        rr[r] = (q < nrows) ? q : (long)(nrows - 1);
    }
    for (int k0 = 0; k0 < K; k0 += 4) {
        float4 xv[R];
#pragma unroll
        for (int r = 0; r < R; ++r) xv[r] = *(const float4*)(X + rr[r] * K + k0);
        float4 wv[8];
#pragma unroll
        for (int j = 0; j < 8; ++j) wv[j] = *(const float4*)&wt[j0 + j][k0];
#pragma unroll
        for (int r = 0; r < R; ++r)
#pragma unroll
            for (int j = 0; j < 8; ++j) {
                acc[r][j] += xv[r].x * wv[j].x;
                acc[r][j] += xv[r].y * wv[j].y;
                acc[r][j] += xv[r].z * wv[j].z;
                acc[r][j] += xv[r].w * wv[j].w;
            }
    }
#pragma unroll
    for (int r = 0; r < R; ++r) {
        long row = rowbase + r;
        if (row < nrows) {
            float dv = dinv ? dinv[row] : 1.0f;
            float o[8];
#pragma unroll
            for (int j = 0; j < 8; ++j) {
                float v = acc[r][j];
                if (bias) v += bias[j0 + j];
                o[j] = v * dv;
            }
            if constexpr (sizeof(OutT) == 4) {
                float4 o0 = make_float4(o[0], o[1], o[2], o[3]);
                float4 o1 = make_float4(o[4], o[5], o[6], o[7]);
                *(float4*)&Y[row * COUT + j0] = o0;
                *(float4*)&Y[row * COUT + j0 + 4] = o1;
            } else {
                uint4 u;
                u.x = (unsigned)f2bf(o[0]) | ((unsigned)f2bf(o[1]) << 16);
                u.y = (unsigned)f2bf(o[2]) | ((unsigned)f2bf(o[3]) << 16);
                u.z = (unsigned)f2bf(o[4]) | ((unsigned)f2bf(o[5]) << 16);
                u.w = (unsigned)f2bf(o[6]) | ((unsigned)f2bf(o[7]) << 16);
                *(uint4*)&Y[row * COUT + j0] = u;
            }
        }
    }
}

// ------- GCN aggregation: 8 lanes/node, ushort4 (dwordx2) gathers, 4-window -------
// xwd4: bf16 quads as uint2, row stride 8. Lane owns features 4*f4 .. 4*f4+3.

template <typename OutT>
__global__ __launch_bounds__(256) void agg_conv_k(const uint2* __restrict__ xwd4,
                                                  const unsigned* __restrict__ adj,
                                                  const int* __restrict__ rowptr4,
                                                  const float* __restrict__ dinv,
                                                  const float* __restrict__ bias,
                                                  OutT* __restrict__ out, int n) {
    int t = threadIdx.x;
    int node = blockIdx.x * 32 + (t >> 3);
    int f4 = t & 7;
    if (node >= n) return;
    int e0 = rowptr4[node * 4];
    int e1 = rowptr4[node * 4 + 4];
    float a0 = 0.f, a1 = 0.f, a2 = 0.f, a3 = 0.f;
    for (int e = e0; e < e1; e += 4) {
        int end1 = e1 - 1;
        int i1 = min(e + 1, end1), i2 = min(e + 2, end1), i3 = min(e + 3, end1);
        unsigned s0 = adj[e] & 0x3FFFF, s1 = adj[i1] & 0x3FFFF;
        unsigned s2 = adj[i2] & 0x3FFFF, s3 = adj[i3] & 0x3FFFF;
        uint2 u0 = xwd4[s0 * 8 + f4];
        uint2 u1 = xwd4[s1 * 8 + f4];
        uint2 u2 = xwd4[s2 * 8 + f4];
        uint2 u3 = xwd4[s3 * 8 + f4];
        bool v1 = e + 1 < e1, v2 = e + 2 < e1, v3 = e + 3 < e1;
        u1.x = v1 ? u1.x : 0u; u1.y = v1 ? u1.y : 0u;
        u2.x = v2 ? u2.x : 0u; u2.y = v2 ? u2.y : 0u;
        u3.x = v3 ? u3.x : 0u; u3.y = v3 ? u3.y : 0u;
        a0 += (bflo(u0.x) + bflo(u1.x)) + (bflo(u2.x) + bflo(u3.x));
        a1 += (bfhi(u0.x) + bfhi(u1.x)) + (bfhi(u2.x) + bfhi(u3.x));
        a2 += (bflo(u0.y) + bflo(u1.y)) + (bflo(u2.y) + bflo(u3.y));
        a3 += (bfhi(u0.y) + bfhi(u1.y)) + (bfhi(u2.y) + bfhi(u3.y));
    }
    float dvn = dinv[node];
    float degv = (float)(e1 - e0) + 1.0f;
    float sself = 1.0f / (dvn * degv);  // xw[node] = xwd[node]/dvn
    uint2 un = xwd4[node * 8 + f4];
    int c0i = 4 * f4;
    float v0 = fmaxf(dvn * a0 + bflo(un.x) * sself + bias[c0i], 0.0f);
    float v1 = fmaxf(dvn * a1 + bfhi(un.x) * sself + bias[c0i + 1], 0.0f);
    float v2 = fmaxf(dvn * a2 + bflo(un.y) * sself + bias[c0i + 2], 0.0f);
    float v3 = fmaxf(dvn * a3 + bfhi(un.y) * sself + bias[c0i + 3], 0.0f);
    if constexpr (sizeof(OutT) == 4) {
        *(float4*)&out[node * 32 + c0i] = make_float4(v0, v1, v2, v3);
    } else {
        uint2 w;
        w.x = (unsigned)f2bf(v0) | ((unsigned)f2bf(v1) << 16);
        w.y = (unsigned)f2bf(v2) | ((unsigned)f2bf(v3) << 16);
        ((uint2*)out)[node * 8 + f4] = w;
    }
}

// ---- fused rs aggregation: per-run 4-windows, ushort4 gathers, 8 lanes/node ----
#define RUN_ACC4(START, END, A)                                             \
    for (int e = (START); e < (END); e += 4) {                              \
        int end1 = (END) - 1;                                               \
        int i1 = min(e + 1, end1), i2 = min(e + 2, end1), i3 = min(e + 3, end1); \
        unsigned s0 = adj[e] & 0x3FFFF, s1 = adj[i1] & 0x3FFFF;             \
        unsigned s2 = adj[i2] & 0x3FFFF, s3 = adj[i3] & 0x3FFFF;            \
        uint2 u0 = h2q[s0 * 8 + f4];                                        \
        uint2 u1 = h2q[s1 * 8 + f4];                                        \
        uint2 u2 = h2q[s2 * 8 + f4];                                        \
        uint2 u3 = h2q[s3 * 8 + f4];                                        \
        bool v1 = e + 1 < (END), v2 = e + 2 < (END), v3 = e + 3 < (END);    \
        u1.x = v1 ? u1.x : 0u; u1.y = v1 ? u1.y : 0u;                       \
        u2.x = v2 ? u2.x : 0u; u2.y = v2 ? u2.y : 0u;                       \
        u3.x = v3 ? u3.x : 0u; u3.y = v3 ? u3.y : 0u;                       \
        (A).x += (bflo(u0.x) + bflo(u1.x)) + (bflo(u2.x) + bflo(u3.x));     \
        (A).y += (bfhi(u0.x) + bfhi(u1.x)) + (bfhi(u2.x) + bfhi(u3.x));     \
        (A).z += (bflo(u0.y) + bflo(u1.y)) + (bflo(u2.y) + bflo(u3.y));     \
        (A).w += (bfhi(u0.y) + bfhi(u1.y)) + (bfhi(u2.y) + bfhi(u3.y));     \
    }

__global__ __launch_bounds__(256) void agg_rs_fused_k(const uint2* __restrict__ h2q,
                                                      const unsigned* __restrict__ adj,
                                                      const int* __restrict__ rowptr4,
                                                      const float* __restrict__ Wl,
                                                      const float* __restrict__ bl,
                                                      float* __restrict__ out, int n) {
    constexpr int AS = 132;          // accs stride: 132 % 32 = 4 -> no cross-group conflict
    __shared__ float wls[32][128];   // Wl[j][c], 16 KB
    __shared__ float bls[128];
    __shared__ float accs[32][AS];   // per-node A_q staging, 16.9 KB
    int t = threadIdx.x;
    for (int i = t; i < 4096; i += 256) wls[i >> 7][i & 127] = Wl[i];
    if (t < 128) bls[t] = bl[t];
    __syncthreads();

    int nl = t >> 3;
    int f4 = t & 7;
    int c0i = 4 * f4;
    int node = blockIdx.x * 32 + nl;
    if (node >= n) return;
    int4 rp = *(const int4*)&rowptr4[node * 4];
    int e4 = rowptr4[node * 4 + 4];
    float4 a0 = make_float4(0.f, 0.f, 0.f, 0.f);
    float4 a1 = a0, a2 = a0, a3 = a0;
    RUN_ACC4(rp.x, rp.y, a0)
    RUN_ACC4(rp.y, rp.z, a1)
    RUN_ACC4(rp.z, rp.w, a2)
    RUN_ACC4(rp.w, e4, a3)

    accs[nl][c0i] = a0.x;      accs[nl][c0i + 1] = a0.y;
    accs[nl][c0i + 2] = a0.z;  accs[nl][c0i + 3] = a0.w;
    accs[nl][32 + c0i] = a1.x;     accs[nl][32 + c0i + 1] = a1.y;
    accs[nl][32 + c0i + 2] = a1.z; accs[nl][32 + c0i + 3] = a1.w;
    accs[nl][64 + c0i] = a2.x;     accs[nl][64 + c0i + 1] = a2.y;
    accs[nl][64 + c0i + 2] = a2.z; accs[nl][64 + c0i + 3] = a2.w;
    accs[nl][96 + c0i] = a3.x;     accs[nl][96 + c0i + 1] = a3.y;
    accs[nl][96 + c0i + 2] = a3.z; accs[nl][96 + c0i + 3] = a3.w;
    // wave-local LDS write->read within the 8-lane group (lockstep)
    float m0 = (float)(rp.y - rp.x), m1 = (float)(rp.z - rp.y);
    float m2 = (float)(rp.w - rp.z), m3 = (float)(e4 - rp.w);
    float o0 = m0 * bls[c0i] + m1 * bls[32 + c0i] + m2 * bls[64 + c0i] + m3 * bls[96 + c0i];
    float o1 = m0 * bls[c0i + 1] + m1 * bls[32 + c0i + 1] + m2 * bls[64 + c0i + 1] + m3 * bls[96 + c0i + 1];
    float o2 = m0 * bls[c0i + 2] + m1 * bls[32 + c0i + 2] + m2 * bls[64 + c0i + 2] + m3 * bls[96 + c0i + 2];
    float o3 = m0 * bls[c0i + 3] + m1 * bls[32 + c0i + 3] + m2 * bls[64 + c0i + 3] + m3 * bls[96 + c0i + 3];
#pragma unroll 8
    for (int j = 0; j < 32; ++j) {
        float q0 = accs[nl][j], q1 = accs[nl][32 + j];
        float q2 = accs[nl][64 + j], q3 = accs[nl][96 + j];
        float4 w0 = *(const float4*)&wls[j][c0i];
        float4 w1 = *(const float4*)&wls[j][32 + c0i];
        float4 w2 = *(const float4*)&wls[j][64 + c0i];
        float4 w3 = *(const float4*)&wls[j][96 + c0i];
        o0 += q0 * w0.x + q1 * w1.x + q2 * w2.x + q3 * w3.x;
        o1 += q0 * w0.y + q1 * w1.y + q2 * w2.y + q3 * w3.y;
        o2 += q0 * w0.z + q1 * w1.z + q2 * w2.z + q3 * w3.z;
        o3 += q0 * w0.w + q1 * w1.w + q2 * w2.w + q3 * w3.w;
    }
    float c = fmaxf((float)(e4 - rp.x), 1.0f);
    float ic = 1.0f / c;
    *(float4*)&out[node * 32 + c0i] = make_float4(o0 * ic, o1 * ic, o2 * ic, o3 * ic);
}

// ---------------- graph pooling (batch sorted: boundary-atomic trick) ----------------

__global__ __launch_bounds__(256) void graph_sum_k(const float* __restrict__ agg,
                                                   const int* __restrict__ batch,
                                                   float* __restrict__ gsum, int n) {
    const int CHUNK = 128;
    int t = threadIdx.x;
    int f = t & 31;
    int j = t >> 5;
    long base = (long)blockIdx.x * (8 * CHUNK) + (long)j * CHUNK;
    if (base >= n) return;
    int end = (int)((n - base < CHUNK) ? (n - base) : CHUNK);
    int cur = batch[base];
    float acc = 0.0f;
    for (int i = 0; i < end; ++i) {
        int b = batch[base + i];
        if (b != cur) {
            atomicAdd(&gsum[cur * 32 + f], acc);
            acc = 0.0f;
            cur = b;
        }
        acc += agg[(base + i) * 32 + f];
    }
    atomicAdd(&gsum[cur * 32 + f], acc);
}

// ---------------- final MLP head ----------------

__global__ __launch_bounds__(256) void mlp_k(const float* __restrict__ gsum,
                                             const int* __restrict__ gcnt,
                                             const float* __restrict__ Wm1,
                                             const float* __restrict__ bm1,
                                             const float* __restrict__ Wm2,
                                             const float* __restrict__ bm2,
                                             float* __restrict__ out, int Gn) {
    __shared__ float w1[1024];
    __shared__ float w2[32];
    __shared__ float b1s[32];
    int t = threadIdx.x;
    for (int i = t; i < 1024; i += 256) w1[i] = Wm1[i];
    if (t < 32) {
        w2[t] = Wm2[t];
        b1s[t] = bm1[t];
    }
    __syncthreads();
    if (t < Gn) {
        float inv = 1.0f / fmaxf((float)gcnt[t], 1.0f);
        float gm[32];
#pragma unroll
        for (int k = 0; k < 32; ++k) gm[k] = gsum[t * 32 + k] * inv;
        float o = bm2[0];
        for (int j = 0; j < 32; ++j) {
            float h = b1s[j];
#pragma unroll
            for (int k = 0; k < 32; ++k) h += gm[k] * w1[k * 32 + j];
            o += fmaxf(h, 0.0f) * w2[j];
        }
        out[t] = 1.0f / (1.0f + expf(-o));
    }
}

// ---------------- launch ----------------

extern "C" void kernel_launch(void* const* d_in, const int* in_sizes, int n_in,
                              void* d_out, int out_size, void* d_ws, size_t ws_size,
                              hipStream_t stream) {
    const float* x = (const float*)d_in[0];
    const int* ei = (const int*)d_in[1];
    const int* ea = (const int*)d_in[2];
    const int* batch = (const int*)d_in[3];
    const float* W1 = (const float*)d_in[4];
    const float* b1 = (const float*)d_in[5];
    const float* W2 = (const float*)d_in[6];
    const float* b2 = (const float*)d_in[7];
    const float* Wl = (const float*)d_in[8];
    const float* bl = (const float*)d_in[9];
    const float* Wm1 = (const float*)d_in[10];
    const float* bm1 = (const float*)d_in[11];
    const float* Wm2 = (const float*)d_in[12];
    const float* bm2 = (const float*)d_in[13];

    const int N = in_sizes[3];
    const int E = in_sizes[2];
    const int Gn = out_size;
    const int NBUCKET = CDIV(N, 512);

    char* ws = (char*)d_ws;
    size_t off = 0;
    auto alloc = [&](size_t bytes) -> void* {
        void* p = ws + off;
        off = (off + bytes + 255) & ~(size_t)255;
        return p;
    };
    int* rowptr4 = (int*)alloc((size_t)(4 * N + 4) * 4);
    float* dinv = (float*)alloc((size_t)N * 4);
    int* bcnt = (int*)alloc(512 * 4);
    int* bbase = (int*)alloc(513 * 4);
    int* bcur = (int*)alloc(512 * 4);
    unsigned* adj = (unsigned*)alloc((size_t)E * 4);
    float* gsum = (float*)alloc((size_t)Gn * 32 * 4);
    int* gcnt = (int*)alloc((size_t)Gn * 4);
    float* bufA = (float*)alloc((size_t)N * 32 * 4);
    float* bufB = (float*)alloc((size_t)N * 32 * 4);
    ushort* xw_bf = (ushort*)alloc((size_t)N * 32 * 2);
    ushort* h2bf = (ushort*)alloc((size_t)N * 32 * 2);
    unsigned long long* tmp = (unsigned long long*)alloc((size_t)E * 8);

    // Workspace / bucket-capacity guard (output stays zero -> absmax ~0.5 signature).
    if (off > ws_size || NBUCKET > 512) return;

    hipMemsetAsync(bcnt, 0, 512 * 4, stream);
    hipMemsetAsync(gsum, 0, (size_t)Gn * 32 * 4, stream);

    coarse_hist_k<<<400, 256, 0, stream>>>(ei + E, bcnt, E, NBUCKET);
    bucket_scan_k<<<1, 256, 0, stream>>>(bcnt, bbase, bcur, NBUCKET, E);
    binA_k<<<CDIV(E, TILE_A), 256, 0, stream>>>(ei, ea, bcur, tmp, E);
    binB_k<<<NBUCKET, 256, 0, stream>>>(tmp, bbase, adj, rowptr4, dinv, N, E);
    gbounds_k<<<CDIV(Gn, 256), 256, 0, stream>>>(batch, gcnt, N, Gn);

    // conv1: xwd1 = dinv * (x@W1) in bf16; gather (ushort4 lanes); h1 f32
    gemm_rk<128, 32, 1, ushort><<<CDIV(N, 64), 256, 0, stream>>>(x, W1, nullptr, dinv, xw_bf, N);
    agg_conv_k<float><<<CDIV(N, 32), 256, 0, stream>>>((const uint2*)xw_bf, adj, rowptr4,
                                                       dinv, b1, bufB, N);
    // conv2: xwd2 = dinv * (h1@W2) in bf16; gather; h2 bf16
    gemm_rk<32, 32, 1, ushort><<<CDIV(N, 64), 256, 0, stream>>>(bufB, W2, nullptr, dinv, xw_bf, N);
    agg_conv_k<ushort><<<CDIV(N, 32), 256, 0, stream>>>((const uint2*)xw_bf, adj, rowptr4,
                                                        dinv, b2, h2bf, N);
    // fused: agg_rs without materializing hl = h2 @ Wl (ushort4 gathers)
    agg_rs_fused_k<<<CDIV(N, 32), 256, 0, stream>>>((const uint2*)h2bf, adj, rowptr4,
                                                    Wl, bl, bufA, N);
    // graph mean + head
    graph_sum_k<<<CDIV(N, 1024), 256, 0, stream>>>(bufA, batch, gsum, N);
    mlp_k<<<1, 256, 0, stream>>>(gsum, gcnt, Wm1, bm1, Wm2, bm2, (float*)d_out, Gn);
}